// Round 13
// baseline (95.618 us; speedup 1.0000x reference)
//
#include <hip/hip_runtime.h>
#include <stdint.h>

// ---------------------------------------------------------------------------
// SelfAttention: QKV proj (fp32 -> bf16 MFMA GEMM) + causal flash attention.
// B=8, S=2048, D=256. out fp32 [B,S,D].
//
// ws: Qb bf16 [B][S][D] linear (pre-scaled 1/16)
//     Ka bf16 fragment layout [B][u:64][c:16][l:64][j:8]
//     Vf bf16 fragment layout [B][u:64][c:2][dt:8][l:64][j:8]
//     Wf bf16 fragment layout [widx:3][kk:8][nb:16][l:64][j:8]
//     Pb bf16 partials [B][32][64][256], ML f32 [B][32][2][64][2].
//
// Round 13:
//  - attn: R12 structure + EARLY RELEASE: lgkm+barrier+stage(u+2) moved to
//    right after the V register loads (all LDS reads of buf retired there),
//    so staging overlaps softmax+pack+PV instead of serializing after PV.
//  - proj: 16-row blocks, grid 1024 -> 4 blocks/CU (16 waves/CU TLP),
//    barrier-free W-from-L2 inner loop (R12), R8's 16-row epilogues.
// ---------------------------------------------------------------------------

typedef __attribute__((ext_vector_type(8)))  short bf16x8;
typedef __attribute__((ext_vector_type(4)))  float f32x4;
typedef __attribute__((ext_vector_type(16))) float f32x16;
typedef __attribute__((ext_vector_type(4)))  unsigned int u32x4;

#define NEGF  -3.0e38f
#define MINIT -1.0e30f

__device__ __forceinline__ unsigned short f2bf(float f){
  union { float f; unsigned u; } v; v.f = f;
  unsigned r = v.u + 0x7FFFu + ((v.u >> 16) & 1u);   // RNE
  return (unsigned short)(r >> 16);
}
__device__ __forceinline__ unsigned pk2(float a, float b){
  return (unsigned)f2bf(a) | ((unsigned)f2bf(b) << 16);
}
__device__ __forceinline__ float bf2f(unsigned short h){
  union { unsigned u; float f; } v; v.u = ((unsigned)h) << 16; return v.f;
}

// ---------------------------------------------------------------------------
// Kernel 0: weight convert -> lane-linear fragment layout Wf.
// Wf[(((widx*8+kk)*16+nb)*64 + hi*16+lo)*8 + j] = W[nb*16+lo][kk*32+hi*8+j]
// ---------------------------------------------------------------------------
__global__ void wconv_kernel(const float* __restrict__ WQ, const float* __restrict__ WK,
                             const float* __restrict__ WV, unsigned short* __restrict__ Wf)
{
  const int widx = blockIdx.x, kk = blockIdx.y;
  const int t = threadIdx.x;
  const int nb = t >> 4, lo = t & 15;
  const float* W = (widx==0) ? WQ : ((widx==1) ? WK : WV);
  const float* src = W + (size_t)(nb*16 + lo)*256 + kk*32;
  unsigned short* dst = Wf + (((size_t)(widx*8 + kk)*16 + nb)*64)*8;
#pragma unroll
  for (int hi=0; hi<4; ++hi){
    float4 a = *reinterpret_cast<const float4*>(src + hi*8);
    float4 c = *reinterpret_cast<const float4*>(src + hi*8 + 4);
    uint4 v; v.x = pk2(a.x,a.y); v.y = pk2(a.z,a.w); v.z = pk2(c.x,c.y); v.w = pk2(c.z,c.w);
    *reinterpret_cast<uint4*>(dst + ((size_t)(hi*16 + lo))*8) = v;
  }
}

// ---------------------------------------------------------------------------
// Kernel 1: QKV projection, barrier-free, 16-row blocks, grid 1024 (4/CU).
// A staged once in LDS (swizzled); B fragments direct from L2 per k-iter.
// ---------------------------------------------------------------------------
__global__ __launch_bounds__(256, 4) void qkv_proj_kernel(
    const float* __restrict__ E, const unsigned short* __restrict__ Wf,
    unsigned short* __restrict__ Qb, unsigned short* __restrict__ Ka,
    unsigned short* __restrict__ Vf)
{
  __shared__ unsigned short As[16*256];     // 8KB, granule g' = g ^ (row&7)

  const int m0 = blockIdx.x * 16;
  const int b  = m0 >> 11;
  const int sb = m0 & 2047;
  const int u  = sb >> 5;                   // kv unit
  const int h  = (sb >> 4) & 1;             // 16-row half of the unit
  const int t = threadIdx.x, lane = t & 63, w = t >> 6;
  const int hi = lane >> 4, lo = lane & 15;

  {  // stage A once: 16 threads/row, 16 floats each
    const int r = t >> 4, cg = t & 15;
    const float* ga = E + (size_t)(m0 + r)*256 + cg*16;
#pragma unroll
    for (int gg=0; gg<2; ++gg){
      float4 x = *reinterpret_cast<const float4*>(ga + gg*8);
      float4 y = *reinterpret_cast<const float4*>(ga + gg*8 + 4);
      uint4 v; v.x = pk2(x.x,x.y); v.y = pk2(x.z,x.w); v.z = pk2(y.x,y.y); v.w = pk2(y.z,y.w);
      const int g = cg*2 + gg;
      *reinterpret_cast<uint4*>((char*)As + r*512 + ((g ^ (r & 7)) << 4)) = v;
    }
  }
  __syncthreads();   // the ONLY block-wide sync

  const f32x4 fzero = {0.f,0.f,0.f,0.f};
  const char* Wfb = (const char*)Wf;

  for (int widx=0; widx<3; ++widx){
    f32x4 acc[4];
#pragma unroll
    for (int f=0;f<4;f++) acc[f] = fzero;

#pragma unroll 2
    for (int kk=0; kk<8; ++kk){
      const char* wp = Wfb + ((size_t)((widx*8 + kk)*16 + w*4))*1024 + lane*16;
      bf16x8 bfr[4];
#pragma unroll
      for (int f=0;f<4;f++)
        bfr[f] = *reinterpret_cast<const bf16x8*>(wp + f*1024);
      bf16x8 afr = *reinterpret_cast<const bf16x8*>(
          (const char*)As + lo*512 + (((kk*4 + hi) ^ (lo & 7)) << 4));
#pragma unroll
      for (int f=0;f<4;f++)
        acc[f] = __builtin_amdgcn_mfma_f32_16x16x32_bf16(afr, bfr[f], acc[f], 0,0,0);
    }

    // epilogues (C/D: row = hi*4+r, col = w*64+f*16+lo)
    if (widx == 0){
#pragma unroll
      for (int f=0;f<4;f++){
        const int col = w*64 + f*16 + lo;
#pragma unroll
        for (int r=0;r<4;r++)
          Qb[(size_t)(m0 + hi*4 + r)*256 + col] = f2bf(acc[f][r]*0.0625f);
      }
    } else if (widx == 1){
      unsigned short* Kab = Ka + (size_t)b*524288 + (size_t)u*8192;
#pragma unroll
      for (int f=0;f<4;f++){
        const int c = w*4 + f;
        const int j = lo & 7;
        const int lb = 32*(lo>>3) + h*16 + hi*4;
#pragma unroll
        for (int r=0;r<4;r++)
          Kab[(size_t)(c*64 + lb + r)*8 + j] = f2bf(acc[f][r]);
      }
    } else {
      unsigned short* Vfb = Vf + (size_t)b*524288;
#pragma unroll
      for (int f=0;f<4;f++){
        const int d  = w*64 + f*16 + lo;
        const int dt = d >> 5;
        const int l  = 32*(hi&1) + (d&31);
        const int j0 = 4*(hi>>1);
        unsigned short* vp = Vfb + ((size_t)((u*2 + h)*8 + dt)*64 + l)*8 + j0;
        uint2 pw; pw.x = pk2(acc[f][0], acc[f][1]);
        pw.y = pk2(acc[f][2], acc[f][3]);
        *reinterpret_cast<uint2*>(vp) = pw;
      }
    }
  }
}

// ---------------------------------------------------------------------------
// Kernel 2: causal flash attention — R12 structure + early buffer release.
// Grid 512 (sched=1) / 256. Waves (qs,dh). K+V staged via global_load_lds,
// double-buffered, counted vmcnt(8). 2 chunks/tile, big-first.
// mode: 0 final->Out; 1 chunk0 raw f32->Out + ML; 2 chunk1 bf16->Pb + ML.
// ---------------------------------------------------------------------------
__global__ __launch_bounds__(256, 2) void attn_kernel(
    const unsigned short* __restrict__ Qb, const unsigned short* __restrict__ Ka,
    const unsigned short* __restrict__ Vf, float* __restrict__ Out,
    const int sched, unsigned short* __restrict__ Pb, float* __restrict__ ML)
{
  __shared__ char Lds[2][32768];    // per buf: K 16KB + V 16KB

  const int bid  = blockIdx.x;
  const int b    = bid & 7;                   // batch == XCD
  const int slot = bid >> 3;
  int tau, chunk, mode, u0, u1;
  if (sched){
    const int ts = slot >> 1; chunk = slot & 1;      // big-first
    tau = (ts < 16) ? (31 - ts) : (ts - 16);
    u0 = chunk ? (tau + 1) : 0;
    u1 = chunk ? (2*tau + 2) : (tau + 1);
    mode = 1 + chunk;
  } else {
    tau = 31 - slot; chunk = 0; u0 = 0; u1 = 2*tau + 2; mode = 0;
  }
  const int Qbase = tau * 64;

  const int t = threadIdx.x;
  const int lane = t & 63, w = t >> 6;
  const int qs = w >> 1, dh = w & 1;
  const int l31 = lane & 31, h5 = lane >> 5;
  const int q_l = Qbase + qs*32 + l31;
  const int diagu = 2*tau + qs;               // first unit needing a mask

  const char* Kab = (const char*)Ka + (size_t)b*1048576;
  const char* Vfb = (const char*)Vf + (size_t)b*1048576;

  auto stage = [&](int uu, int buf){
    const char* gk = Kab + (size_t)uu*16384;
    const char* gv = Vfb + (size_t)uu*16384;
    char* lk = Lds[buf];
    char* lv = Lds[buf] + 16384;
#pragma unroll
    for (int i=0;i<4;i++){
      const int off = i*4096 + t*16;
      __builtin_amdgcn_global_load_lds(
        (const __attribute__((address_space(1))) unsigned int*)(gk + off),
        (__attribute__((address_space(3))) unsigned int*)(lk + off), 16, 0, 0);
      __builtin_amdgcn_global_load_lds(
        (const __attribute__((address_space(1))) unsigned int*)(gv + off),
        (__attribute__((address_space(3))) unsigned int*)(lv + off), 16, 0, 0);
    }
  };

  // Q fragments (QK B-operand)
  bf16x8 qf[16];
  {
    const unsigned short* Qp = Qb + ((size_t)(b*2048 + q_l))*256 + h5*8;
#pragma unroll
    for (int c=0;c<16;c++) qf[c] = *reinterpret_cast<const bf16x8*>(Qp + c*16);
  }

  const f32x16 z16 = {0.f,0.f,0.f,0.f,0.f,0.f,0.f,0.f,0.f,0.f,0.f,0.f,0.f,0.f,0.f,0.f};
  f32x16 accO[4];
#pragma unroll
  for (int i=0;i<4;i++) accO[i] = z16;
  float m_run = MINIT, l_run = 0.f;

  stage(u0, 0);
  if (u0 + 1 < u1) stage(u0 + 1, 1);

  for (int u = u0; u < u1; ++u){
    const int buf = (u - u0) & 1;
    // counted vmcnt: this unit's 8 loads retired; next unit's 8 stay in flight
    if (u + 1 < u1) asm volatile("s_waitcnt vmcnt(8)" ::: "memory");
    else            asm volatile("s_waitcnt vmcnt(0)" ::: "memory");
    __builtin_amdgcn_sched_barrier(0);
    __builtin_amdgcn_s_barrier();
    __builtin_amdgcn_sched_barrier(0);

    const char* kt = Lds[buf];
    const char* lv = Lds[buf] + 16384 + dh*4096 + lane*16;

    // ---- QK^T swapped: S^T[kv][q] ----
    f32x16 sv0 = z16, sv1 = z16;
#pragma unroll
    for (int c=0;c<16;c+=2){
      bf16x8 a0 = *reinterpret_cast<const bf16x8*>(kt + c*1024 + lane*16);
      bf16x8 a1 = *reinterpret_cast<const bf16x8*>(kt + (c+1)*1024 + lane*16);
      sv0 = __builtin_amdgcn_mfma_f32_32x32x16_bf16(a0, qf[c],   sv0, 0,0,0);
      sv1 = __builtin_amdgcn_mfma_f32_32x32x16_bf16(a1, qf[c+1], sv1, 0,0,0);
    }
    f32x16 s16 = sv0 + sv1;

    // ---- V fragments from LDS (last LDS reads of this buf) ----
    bf16x8 vf0[4], vf1[4];
#pragma unroll
    for (int i=0;i<4;i++){
      vf0[i] = *reinterpret_cast<const bf16x8*>(lv + i*1024);
      vf1[i] = *reinterpret_cast<const bf16x8*>(lv + 8192 + i*1024);
    }

    // ---- EARLY RELEASE: all LDS reads of buf retired -> barrier -> restage.
    // Staging of u+2 now overlaps softmax + pack + PV (register-only).
    asm volatile("s_waitcnt lgkmcnt(0)" ::: "memory");
    __builtin_amdgcn_sched_barrier(0);
    __builtin_amdgcn_s_barrier();
    if (u + 2 < u1) stage(u + 2, buf);

    // ---- causal mask ----
    if (u >= diagu){
      const int kvb = u*32 + 4*h5;
#pragma unroll
      for (int r=0;r<16;r++){
        const int kv = kvb + (r&3) + 8*(r>>2);
        if (kv > q_l) s16[r] = NEGF;
      }
    }

    // ---- in-register softmax (defer-max THR=8) ----
    float t8[8], t4[4];
#pragma unroll
    for (int i=0;i<8;i++) t8[i] = fmaxf(s16[i], s16[i+8]);
#pragma unroll
    for (int i=0;i<4;i++) t4[i] = fmaxf(t8[i], t8[i+4]);
    float pmax = fmaxf(fmaxf(t4[0],t4[1]), fmaxf(t4[2],t4[3]));
    pmax = fmaxf(pmax, __shfl_xor(pmax, 32, 64));

    if (!__all(pmax - m_run <= 8.0f)){
      const float mn = fmaxf(m_run, pmax);
      const float alpha = __expf(m_run - mn);
#pragma unroll
      for (int i=0;i<4;i++) accO[i] *= alpha;
      l_run *= alpha;
      m_run = mn;
    }
    float p[16];
#pragma unroll
    for (int r=0;r<16;r++) p[r] = __expf(s16[r] - m_run);
#pragma unroll
    for (int i=0;i<8;i++) t8[i] = p[i] + p[i+8];
#pragma unroll
    for (int i=0;i<4;i++) t4[i] = t8[i] + t8[i+4];
    float ls = (t4[0]+t4[1]) + (t4[2]+t4[3]);
    ls += __shfl_xor(ls, 32, 64);
    l_run += ls;

    union { bf16x8 v; unsigned u32[4]; } pa0, pa1;
#pragma unroll
    for (int k=0;k<4;k++){
      pa0.u32[k] = pk2(p[2*k],   p[2*k+1]);
      pa1.u32[k] = pk2(p[8+2*k], p[9+2*k]);
    }

    // ---- PV swapped: O^T[d][q] += mfma(V^T, P) (register-only) ----
#pragma unroll
    for (int i=0;i<4;i++){
      accO[i] = __builtin_amdgcn_mfma_f32_32x32x16_bf16(vf0[i], pa0.v, accO[i], 0,0,0);
      accO[i] = __builtin_amdgcn_mfma_f32_32x32x16_bf16(vf1[i], pa1.v, accO[i], 0,0,0);
    }
  }

  // ---- m,l for split chunks ----
  if (mode && dh == 0 && lane < 32){
    float* mlp = ML + ((size_t)(((b*32 + tau)*2 + chunk)*64 + qs*32 + lane))*2;
    mlp[0] = m_run; mlp[1] = l_run;
  }

  __syncthreads();   // all waves past their last LDS reads; Lds[0] reusable

  // ---- LDS-transpose epilogue (per-wave disjoint 8KB regions) ----
  const float inv = (mode == 0) ? 1.0f/(l_run + 1e-9f) : 1.0f;
  float* Tw = (float*)(&Lds[0][0]) + w*2048;
  const int qloc = lane >> 1, dc = (lane & 1) * 16;
#pragma unroll
  for (int i=0;i<4;i++){
#pragma unroll
    for (int r=0;r<16;r++)
      Tw[l31*33 + ((r&3) + 8*(r>>2) + 4*h5)] = accO[i][r] * inv;
    asm volatile("s_waitcnt lgkmcnt(0)" ::: "memory");
    __builtin_amdgcn_sched_barrier(0);
    const float* srcT = &Tw[qloc*33 + dc];
    if (mode < 2){
      float* dst = Out + ((size_t)(b*2048 + Qbase + qs*32 + qloc))*256 + dh*128 + i*32 + dc;
#pragma unroll
      for (int k=0;k<4;k++){
        float4 vv = { srcT[4*k], srcT[4*k+1], srcT[4*k+2], srcT[4*k+3] };
        *reinterpret_cast<float4*>(dst + 4*k) = vv;
      }
    } else {
      unsigned short* pb = Pb + (((size_t)(b*32 + tau)*64 + qs*32 + qloc))*256
                              + dh*128 + i*32 + dc;
      u32x4 w0, w1;
      w0.x = pk2(srcT[0],  srcT[1]);  w0.y = pk2(srcT[2],  srcT[3]);
      w0.z = pk2(srcT[4],  srcT[5]);  w0.w = pk2(srcT[6],  srcT[7]);
      w1.x = pk2(srcT[8],  srcT[9]);  w1.y = pk2(srcT[10], srcT[11]);
      w1.z = pk2(srcT[12], srcT[13]); w1.w = pk2(srcT[14], srcT[15]);
      *reinterpret_cast<u32x4*>(pb)     = w0;
      *reinterpret_cast<u32x4*>(pb + 8) = w1;
    }
    asm volatile("s_waitcnt lgkmcnt(0)" ::: "memory");
    __builtin_amdgcn_sched_barrier(0);
  }
}

// ---------------------------------------------------------------------------
// Kernel 3: exact flash combine of the 2 chunks. Grid 256 (8 b x 32 tiles).
// ---------------------------------------------------------------------------
__global__ void combine_kernel(float* __restrict__ Out, const unsigned short* __restrict__ Pb,
                               const float* __restrict__ ML)
{
  const int b = blockIdx.x & 7, tt = blockIdx.x >> 3;
  const int t = threadIdx.x;
  const int q = t >> 2, dg = (t & 3) * 64;
  const float* mlp = ML + ((size_t)((b*32 + tt)*2)*64)*2;
  const float m0 = mlp[q*2],        l0 = mlp[q*2 + 1];
  const float m1 = mlp[(64+q)*2],   l1 = mlp[(64+q)*2 + 1];
  const float M  = fmaxf(m0, m1);
  const float e0 = __expf(m0 - M), e1 = __expf(m1 - M);
  const float inv = 1.0f/(e0*l0 + e1*l1 + 1e-9f);
  float* O = Out + ((size_t)(b*2048 + tt*64 + q))*256 + dg;
  const unsigned short* P = Pb + ((size_t)((b*32 + tt)*64 + q))*256 + dg;
#pragma unroll
  for (int k=0;k<8;k++){
    float4 a0 = *reinterpret_cast<const float4*>(O + 8*k);
    float4 a1 = *reinterpret_cast<const float4*>(O + 8*k + 4);
    uint4 pvv = *reinterpret_cast<const uint4*>(P + 8*k);
    const unsigned short* us = (const unsigned short*)&pvv;
    float4 o0, o1;
    o0.x = (e0*a0.x + e1*bf2f(us[0]))*inv; o0.y = (e0*a0.y + e1*bf2f(us[1]))*inv;
    o0.z = (e0*a0.z + e1*bf2f(us[2]))*inv; o0.w = (e0*a0.w + e1*bf2f(us[3]))*inv;
    o1.x = (e0*a1.x + e1*bf2f(us[4]))*inv; o1.y = (e0*a1.y + e1*bf2f(us[5]))*inv;
    o1.z = (e0*a1.z + e1*bf2f(us[6]))*inv; o1.w = (e0*a1.w + e1*bf2f(us[7]))*inv;
    *reinterpret_cast<float4*>(O + 8*k)     = o0;
    *reinterpret_cast<float4*>(O + 8*k + 4) = o1;
  }
}

// ---------------------------------------------------------------------------
extern "C" void kernel_launch(void* const* d_in, const int* in_sizes, int n_in,
                              void* d_out, int out_size, void* d_ws, size_t ws_size,
                              hipStream_t stream)
{
  const float* E  = (const float*)d_in[0];
  const float* WQ = (const float*)d_in[1];
  const float* WK = (const float*)d_in[2];
  const float* WV = (const float*)d_in[3];
  const size_t elems = (size_t)8*2048*256;

  unsigned short* Qb = (unsigned short*)d_ws;
  unsigned short* Ka = Qb + elems;
  unsigned short* Vf = Ka + elems;
  unsigned short* Wf = Vf + elems;                       // 196608 ushorts
  const size_t base = 3*elems*2 + 393216;                // 25.56 MB

  const size_t PB = (size_t)8*32*64*256*2;               // 8 MB
  const size_t MLSZ = (size_t)8*32*2*64*2*4;             // 256 KB
  if (ws_size < base) return;
  const int sched = (ws_size >= base + PB + MLSZ) ? 1 : 0;
  unsigned short* Pb = (unsigned short*)((char*)d_ws + base);
  float* ML = (float*)((char*)d_ws + base + PB);

  wconv_kernel<<<dim3(3,8), 256, 0, stream>>>(WQ, WK, WV, Wf);
  qkv_proj_kernel<<<1024, 256, 0, stream>>>(E, Wf, Qb, Ka, Vf);
  attn_kernel<<<sched ? 512 : 256, 256, 0, stream>>>(Qb, Ka, Vf, (float*)d_out, sched, Pb, ML);
  if (sched) combine_kernel<<<256, 256, 0, stream>>>((float*)d_out, Pb, ML);
}

// Round 14
// 85.551 us; speedup vs baseline: 1.1177x; 1.1177x over previous
//
#include <hip/hip_runtime.h>
#include <hip/hip_bf16.h>
#include <stdint.h>

// ---------------------------------------------------------------------------
// SelfAttention: QKV proj (fp32 -> bf16 MFMA GEMM) + causal flash attention.
// B=8, S=2048, D=256. out fp32 [B,S,D].
//
// ws: Qb bf16 [B][S][D] linear (pre-scaled 1/16)
//     Ka bf16 fragment layout [B][u:64][c:16][l:64][j:8]
//     Vf bf16 fragment layout [B][u:64][c:2][dt:8][l:64][j:8]
//     Wb bf16 pre-swizzled weights (B-tile staging format)
//     Pb bf16 partials [B][32][64][256], ML f32 [B][32][2][64][2].
//
// Round 14 (consolidation of best-known components):
//  - wconv+proj: R7/R10 version verbatim (lockstep LDS-staged B via
//    global_load_lds, counted vmcnt(4), 32-row blocks, 3 blocks/CU) —
//    measured 6us faster than the R12 "barrier-free" rewrite.
//  - attn: R12 version verbatim (50.1us, FETCH 12.35MB) with ONE delta:
//    softmax P-pack uses native __float2bfloat16 casts (compiler lowers to
//    v_cvt / v_cvt_pk) instead of manual bit-twiddle RNE (~70 VALU ops ->
//    ~16 per lane per unit).
// ---------------------------------------------------------------------------

typedef __attribute__((ext_vector_type(8)))  short bf16x8;
typedef __attribute__((ext_vector_type(4)))  float f32x4;
typedef __attribute__((ext_vector_type(16))) float f32x16;
typedef __attribute__((ext_vector_type(4)))  unsigned int u32x4;

#define NEGF  -3.0e38f
#define MINIT -1.0e30f

__device__ __forceinline__ unsigned short f2bf(float f){
  union { float f; unsigned u; } v; v.f = f;
  unsigned r = v.u + 0x7FFFu + ((v.u >> 16) & 1u);   // RNE
  return (unsigned short)(r >> 16);
}
__device__ __forceinline__ unsigned pk2(float a, float b){
  return (unsigned)f2bf(a) | ((unsigned)f2bf(b) << 16);
}
// native-cast path (compiler lowers to v_cvt_*_bf16; m240: don't hand-write)
__device__ __forceinline__ unsigned short f2bf_n(float f){
  __hip_bfloat16 h = __float2bfloat16(f);
  return *reinterpret_cast<unsigned short*>(&h);
}
__device__ __forceinline__ unsigned pk2_n(float a, float b){
  return (unsigned)f2bf_n(a) | ((unsigned)f2bf_n(b) << 16);
}
__device__ __forceinline__ float bf2f(unsigned short h){
  union { unsigned u; float f; } v; v.u = ((unsigned)h) << 16; return v.f;
}

// ---------------------------------------------------------------------------
// Kernel 0: weight convert (B-tile staging format for proj). [R7 version]
// ---------------------------------------------------------------------------
__global__ void wconv_kernel(const float* __restrict__ WQ, const float* __restrict__ WK,
                             const float* __restrict__ WV, unsigned short* __restrict__ Wb)
{
  const int widx = blockIdx.x, kk = blockIdx.y, n = threadIdx.x;
  const float* W = (widx==0) ? WQ : ((widx==1) ? WK : WV);
  unsigned short* dst = Wb + (size_t)widx*65536 + kk*8192 + n*32;
#pragma unroll
  for (int gp=0; gp<4; ++gp){
    const int g = gp ^ (n & 3);
    const float* src = W + (size_t)n*256 + kk*32 + g*8;
    float4 a = *reinterpret_cast<const float4*>(src);
    float4 c = *reinterpret_cast<const float4*>(src + 4);
    uint4 v; v.x = pk2(a.x,a.y); v.y = pk2(a.z,a.w); v.z = pk2(c.x,c.y); v.w = pk2(c.z,c.w);
    *reinterpret_cast<uint4*>(dst + gp*8) = v;
  }
}

// ---------------------------------------------------------------------------
// Kernel 1: QKV projection. [R7 version verbatim: 32-row blocks, BK=32,
// counted vmcnt(4), 2 barriers/iter, 3 blocks/CU]
// ---------------------------------------------------------------------------
__global__ __launch_bounds__(256, 3) void qkv_proj_kernel(
    const float* __restrict__ E, const unsigned short* __restrict__ Wb,
    unsigned short* __restrict__ Qb, unsigned short* __restrict__ Ka,
    unsigned short* __restrict__ Vf)
{
  __shared__ unsigned short As[32*256];     // 16KB
  __shared__ unsigned short Bs[2][8192];    // 32KB

  const int m0 = blockIdx.x * 32;
  const int b  = m0 >> 11;
  const int sb = m0 & 2047;
  const int t = threadIdx.x, lane = t & 63, w = t >> 6;
  const int hi = lane >> 4, lo = lane & 15;

  auto stageB = [&](int widx, int kk, int buf){
    const char* src = (const char*)Wb + widx*131072 + kk*16384;
    char* dst = (char*)Bs[buf];
#pragma unroll
    for (int c=0;c<4;c++){
      const int off = c*4096 + t*16;
      __builtin_amdgcn_global_load_lds(
        (const __attribute__((address_space(1))) unsigned int*)(src + off),
        (__attribute__((address_space(3))) unsigned int*)(dst + off), 16, 0, 0);
    }
  };

  stageB(0, 0, 0);
  {
    const int r = t >> 3, c0 = (t & 7) * 32;
    const float* ga = E + (size_t)(m0 + r)*256 + c0;
#pragma unroll
    for (int gg=0; gg<4; ++gg){
      float4 x = *reinterpret_cast<const float4*>(ga + gg*8);
      float4 y = *reinterpret_cast<const float4*>(ga + gg*8 + 4);
      uint4 v; v.x = pk2(x.x,x.y); v.y = pk2(x.z,x.w); v.z = pk2(y.x,y.y); v.w = pk2(y.z,y.w);
      const int g = (t & 7)*4 + gg;
      *reinterpret_cast<uint4*>((char*)As + r*512 + ((g ^ (r & 7)) << 4)) = v;
    }
  }

  const f32x4 fzero = {0.f,0.f,0.f,0.f};
  const int u = sb >> 5;
  for (int widx=0; widx<3; ++widx){
    f32x4 acc[2][4];
#pragma unroll
    for (int mi=0;mi<2;mi++)
#pragma unroll
      for (int f=0;f<4;f++) acc[mi][f] = fzero;
    if (widx) stageB(widx, 0, 0);

    for (int kk=0; kk<8; ++kk){
      const int bb = kk & 1;
      if (kk < 7) stageB(widx, kk+1, bb^1);
      if (kk < 7) asm volatile("s_waitcnt vmcnt(4) lgkmcnt(0)" ::: "memory");
      else        asm volatile("s_waitcnt vmcnt(0) lgkmcnt(0)" ::: "memory");
      __builtin_amdgcn_sched_barrier(0);
      __builtin_amdgcn_s_barrier();
      __builtin_amdgcn_sched_barrier(0);

      bf16x8 afr[2], bfr[4];
#pragma unroll
      for (int mi=0;mi<2;mi++){
        const int r = mi*16 + lo;
        afr[mi] = *reinterpret_cast<const bf16x8*>(
            (const char*)As + r*512 + (((kk*4 + hi) ^ (r & 7)) << 4));
      }
#pragma unroll
      for (int f=0;f<4;f++){
        const int n = w*64 + f*16 + lo;
        bfr[f] = *reinterpret_cast<const bf16x8*>(
            (const char*)Bs[bb] + n*64 + ((hi ^ (n & 3)) << 4));
      }
#pragma unroll
      for (int mi=0;mi<2;mi++)
#pragma unroll
        for (int f=0;f<4;f++)
          acc[mi][f] = __builtin_amdgcn_mfma_f32_16x16x32_bf16(afr[mi], bfr[f], acc[mi][f], 0,0,0);

      asm volatile("s_waitcnt lgkmcnt(0)" ::: "memory");
      __builtin_amdgcn_sched_barrier(0);
      __builtin_amdgcn_s_barrier();
    }

    if (widx == 0){
#pragma unroll
      for (int mi=0;mi<2;mi++)
#pragma unroll
        for (int f=0;f<4;f++){
          const int col = w*64 + f*16 + lo;
#pragma unroll
          for (int r=0;r<4;r++)
            Qb[(size_t)(m0 + mi*16 + hi*4 + r)*256 + col] = f2bf(acc[mi][f][r]*0.0625f);
        }
    } else if (widx == 1){
      unsigned short* Kab = Ka + (size_t)b*524288 + (size_t)u*8192;
#pragma unroll
      for (int mi=0;mi<2;mi++)
#pragma unroll
        for (int f=0;f<4;f++){
          const int c = w*4 + f;
          const int j = lo & 7;
          const int lb = 32*(lo>>3) + mi*16 + hi*4;
#pragma unroll
          for (int r=0;r<4;r++)
            Kab[(size_t)(c*64 + lb + r)*8 + j] = f2bf(acc[mi][f][r]);
        }
    } else {
      unsigned short* Vfb = Vf + (size_t)b*524288;
#pragma unroll
      for (int mi=0;mi<2;mi++)
#pragma unroll
        for (int f=0;f<4;f++){
          const int d  = w*64 + f*16 + lo;
          const int dt = d >> 5;
          const int l  = 32*(hi&1) + (d&31);
          const int j0 = 4*(hi>>1);
          unsigned short* vp = Vfb + ((size_t)((u*2 + mi)*8 + dt)*64 + l)*8 + j0;
          uint2 pw; pw.x = pk2(acc[mi][f][0], acc[mi][f][1]);
          pw.y = pk2(acc[mi][f][2], acc[mi][f][3]);
          *reinterpret_cast<uint2*>(vp) = pw;
        }
    }
  }
}

// ---------------------------------------------------------------------------
// Kernel 2: causal flash attention. [R12 version; only the P-pack changed
// to native casts] Grid 512 (sched=1) / 256. Waves (qs,dh). K+V staged via
// global_load_lds, double-buffered, counted vmcnt(8). 2 chunks/tile.
// mode: 0 final->Out; 1 chunk0 raw f32->Out + ML; 2 chunk1 bf16->Pb + ML.
// ---------------------------------------------------------------------------
__global__ __launch_bounds__(256, 2) void attn_kernel(
    const unsigned short* __restrict__ Qb, const unsigned short* __restrict__ Ka,
    const unsigned short* __restrict__ Vf, float* __restrict__ Out,
    const int sched, unsigned short* __restrict__ Pb, float* __restrict__ ML)
{
  __shared__ char Lds[2][32768];    // per buf: K 16KB + V 16KB

  const int bid  = blockIdx.x;
  const int b    = bid & 7;                   // batch == XCD
  const int slot = bid >> 3;
  int tau, chunk, mode, u0, u1;
  if (sched){
    const int ts = slot >> 1; chunk = slot & 1;      // big-first
    tau = (ts < 16) ? (31 - ts) : (ts - 16);
    u0 = chunk ? (tau + 1) : 0;
    u1 = chunk ? (2*tau + 2) : (tau + 1);
    mode = 1 + chunk;
  } else {
    tau = 31 - slot; chunk = 0; u0 = 0; u1 = 2*tau + 2; mode = 0;
  }
  const int Qbase = tau * 64;

  const int t = threadIdx.x;
  const int lane = t & 63, w = t >> 6;
  const int qs = w >> 1, dh = w & 1;
  const int l31 = lane & 31, h5 = lane >> 5;
  const int q_l = Qbase + qs*32 + l31;
  const int diagu = 2*tau + qs;               // first unit needing a mask

  const char* Kab = (const char*)Ka + (size_t)b*1048576;
  const char* Vfb = (const char*)Vf + (size_t)b*1048576;

  auto stage = [&](int uu, int buf){
    const char* gk = Kab + (size_t)uu*16384;
    const char* gv = Vfb + (size_t)uu*16384;
    char* lk = Lds[buf];
    char* lv = Lds[buf] + 16384;
#pragma unroll
    for (int i=0;i<4;i++){
      const int off = i*4096 + t*16;
      __builtin_amdgcn_global_load_lds(
        (const __attribute__((address_space(1))) unsigned int*)(gk + off),
        (__attribute__((address_space(3))) unsigned int*)(lk + off), 16, 0, 0);
      __builtin_amdgcn_global_load_lds(
        (const __attribute__((address_space(1))) unsigned int*)(gv + off),
        (__attribute__((address_space(3))) unsigned int*)(lv + off), 16, 0, 0);
    }
  };

  // Q fragments (QK B-operand)
  bf16x8 qf[16];
  {
    const unsigned short* Qp = Qb + ((size_t)(b*2048 + q_l))*256 + h5*8;
#pragma unroll
    for (int c=0;c<16;c++) qf[c] = *reinterpret_cast<const bf16x8*>(Qp + c*16);
  }

  const f32x16 z16 = {0.f,0.f,0.f,0.f,0.f,0.f,0.f,0.f,0.f,0.f,0.f,0.f,0.f,0.f,0.f,0.f};
  f32x16 accO[4];
#pragma unroll
  for (int i=0;i<4;i++) accO[i] = z16;
  float m_run = MINIT, l_run = 0.f;

  stage(u0, 0);
  if (u0 + 1 < u1) stage(u0 + 1, 1);

  for (int u = u0; u < u1; ++u){
    const int buf = (u - u0) & 1;
    // counted vmcnt: this unit's 8 loads retired; next unit's 8 stay in flight
    if (u + 1 < u1) asm volatile("s_waitcnt vmcnt(8)" ::: "memory");
    else            asm volatile("s_waitcnt vmcnt(0)" ::: "memory");
    __builtin_amdgcn_sched_barrier(0);
    __builtin_amdgcn_s_barrier();
    __builtin_amdgcn_sched_barrier(0);

    const char* kt = Lds[buf];
    const char* lv = Lds[buf] + 16384 + dh*4096 + lane*16;

    // ---- QK^T swapped: S^T[kv][q] ----
    f32x16 sv0 = z16, sv1 = z16;
#pragma unroll
    for (int c=0;c<16;c+=2){
      bf16x8 a0 = *reinterpret_cast<const bf16x8*>(kt + c*1024 + lane*16);
      bf16x8 a1 = *reinterpret_cast<const bf16x8*>(kt + (c+1)*1024 + lane*16);
      sv0 = __builtin_amdgcn_mfma_f32_32x32x16_bf16(a0, qf[c],   sv0, 0,0,0);
      sv1 = __builtin_amdgcn_mfma_f32_32x32x16_bf16(a1, qf[c+1], sv1, 0,0,0);
    }
    f32x16 s16 = sv0 + sv1;

    // ---- V fragments from LDS ----
    bf16x8 vf0[4], vf1[4];
#pragma unroll
    for (int i=0;i<4;i++){
      vf0[i] = *reinterpret_cast<const bf16x8*>(lv + i*1024);
      vf1[i] = *reinterpret_cast<const bf16x8*>(lv + 8192 + i*1024);
    }

    // ---- causal mask ----
    if (u >= diagu){
      const int kvb = u*32 + 4*h5;
#pragma unroll
      for (int r=0;r<16;r++){
        const int kv = kvb + (r&3) + 8*(r>>2);
        if (kv > q_l) s16[r] = NEGF;
      }
    }

    // ---- in-register softmax (defer-max THR=8) ----
    float t8[8], t4[4];
#pragma unroll
    for (int i=0;i<8;i++) t8[i] = fmaxf(s16[i], s16[i+8]);
#pragma unroll
    for (int i=0;i<4;i++) t4[i] = fmaxf(t8[i], t8[i+4]);
    float pmax = fmaxf(fmaxf(t4[0],t4[1]), fmaxf(t4[2],t4[3]));
    pmax = fmaxf(pmax, __shfl_xor(pmax, 32, 64));

    if (!__all(pmax - m_run <= 8.0f)){
      const float mn = fmaxf(m_run, pmax);
      const float alpha = __expf(m_run - mn);
#pragma unroll
      for (int i=0;i<4;i++) accO[i] *= alpha;
      l_run *= alpha;
      m_run = mn;
    }
    float p[16];
#pragma unroll
    for (int r=0;r<16;r++) p[r] = __expf(s16[r] - m_run);
#pragma unroll
    for (int i=0;i<8;i++) t8[i] = p[i] + p[i+8];
#pragma unroll
    for (int i=0;i<4;i++) t4[i] = t8[i] + t8[i+4];
    float ls = (t4[0]+t4[1]) + (t4[2]+t4[3]);
    ls += __shfl_xor(ls, 32, 64);
    l_run += ls;

    // ---- pack P via native casts (compiler lowers to v_cvt/cvt_pk) ----
    union { bf16x8 v; unsigned u32[4]; } pa0, pa1;
#pragma unroll
    for (int k=0;k<4;k++){
      pa0.u32[k] = pk2_n(p[2*k],   p[2*k+1]);
      pa1.u32[k] = pk2_n(p[8+2*k], p[9+2*k]);
    }

    // ---- PV swapped: O^T[d][q] += mfma(V^T, P) ----
#pragma unroll
    for (int i=0;i<4;i++){
      accO[i] = __builtin_amdgcn_mfma_f32_32x32x16_bf16(vf0[i], pa0.v, accO[i], 0,0,0);
      accO[i] = __builtin_amdgcn_mfma_f32_32x32x16_bf16(vf1[i], pa1.v, accO[i], 0,0,0);
    }

    // ---- all waves done reading buf -> prefetch u+2 into it ----
    asm volatile("s_waitcnt lgkmcnt(0)" ::: "memory");
    __builtin_amdgcn_sched_barrier(0);
    __builtin_amdgcn_s_barrier();
    if (u + 2 < u1) stage(u + 2, buf);
  }

  // ---- m,l for split chunks ----
  if (mode && dh == 0 && lane < 32){
    float* mlp = ML + ((size_t)(((b*32 + tau)*2 + chunk)*64 + qs*32 + lane))*2;
    mlp[0] = m_run; mlp[1] = l_run;
  }

  // ---- LDS-transpose epilogue (Lds[0] reused; all reads drained above) ----
  const float inv = (mode == 0) ? 1.0f/(l_run + 1e-9f) : 1.0f;
  float* Tw = (float*)(&Lds[0][0]) + w*2048;
  const int qloc = lane >> 1, dc = (lane & 1) * 16;
#pragma unroll
  for (int i=0;i<4;i++){
#pragma unroll
    for (int r=0;r<16;r++)
      Tw[l31*33 + ((r&3) + 8*(r>>2) + 4*h5)] = accO[i][r] * inv;
    asm volatile("s_waitcnt lgkmcnt(0)" ::: "memory");
    __builtin_amdgcn_sched_barrier(0);
    const float* srcT = &Tw[qloc*33 + dc];
    if (mode < 2){
      float* dst = Out + ((size_t)(b*2048 + Qbase + qs*32 + qloc))*256 + dh*128 + i*32 + dc;
#pragma unroll
      for (int k=0;k<4;k++){
        float4 vv = { srcT[4*k], srcT[4*k+1], srcT[4*k+2], srcT[4*k+3] };
        *reinterpret_cast<float4*>(dst + 4*k) = vv;
      }
    } else {
      unsigned short* pb = Pb + (((size_t)(b*32 + tau)*64 + qs*32 + qloc))*256
                              + dh*128 + i*32 + dc;
      u32x4 w0, w1;
      w0.x = pk2_n(srcT[0],  srcT[1]);  w0.y = pk2_n(srcT[2],  srcT[3]);
      w0.z = pk2_n(srcT[4],  srcT[5]);  w0.w = pk2_n(srcT[6],  srcT[7]);
      w1.x = pk2_n(srcT[8],  srcT[9]);  w1.y = pk2_n(srcT[10], srcT[11]);
      w1.z = pk2_n(srcT[12], srcT[13]); w1.w = pk2_n(srcT[14], srcT[15]);
      *reinterpret_cast<u32x4*>(pb)     = w0;
      *reinterpret_cast<u32x4*>(pb + 8) = w1;
    }
    asm volatile("s_waitcnt lgkmcnt(0)" ::: "memory");
    __builtin_amdgcn_sched_barrier(0);
  }
}

// ---------------------------------------------------------------------------
// Kernel 3: exact flash combine of the 2 chunks. Grid 256 (8 b x 32 tiles).
// ---------------------------------------------------------------------------
__global__ void combine_kernel(float* __restrict__ Out, const unsigned short* __restrict__ Pb,
                               const float* __restrict__ ML)
{
  const int b = blockIdx.x & 7, tt = blockIdx.x >> 3;
  const int t = threadIdx.x;
  const int q = t >> 2, dg = (t & 3) * 64;
  const float* mlp = ML + ((size_t)((b*32 + tt)*2)*64)*2;
  const float m0 = mlp[q*2],        l0 = mlp[q*2 + 1];
  const float m1 = mlp[(64+q)*2],   l1 = mlp[(64+q)*2 + 1];
  const float M  = fmaxf(m0, m1);
  const float e0 = __expf(m0 - M), e1 = __expf(m1 - M);
  const float inv = 1.0f/(e0*l0 + e1*l1 + 1e-9f);
  float* O = Out + ((size_t)(b*2048 + tt*64 + q))*256 + dg;
  const unsigned short* P = Pb + ((size_t)((b*32 + tt)*64 + q))*256 + dg;
#pragma unroll
  for (int k=0;k<8;k++){
    float4 a0 = *reinterpret_cast<const float4*>(O + 8*k);
    float4 a1 = *reinterpret_cast<const float4*>(O + 8*k + 4);
    uint4 pvv = *reinterpret_cast<const uint4*>(P + 8*k);
    const unsigned short* us = (const unsigned short*)&pvv;
    float4 o0, o1;
    o0.x = (e0*a0.x + e1*bf2f(us[0]))*inv; o0.y = (e0*a0.y + e1*bf2f(us[1]))*inv;
    o0.z = (e0*a0.z + e1*bf2f(us[2]))*inv; o0.w = (e0*a0.w + e1*bf2f(us[3]))*inv;
    o1.x = (e0*a1.x + e1*bf2f(us[4]))*inv; o1.y = (e0*a1.y + e1*bf2f(us[5]))*inv;
    o1.z = (e0*a1.z + e1*bf2f(us[6]))*inv; o1.w = (e0*a1.w + e1*bf2f(us[7]))*inv;
    *reinterpret_cast<float4*>(O + 8*k)     = o0;
    *reinterpret_cast<float4*>(O + 8*k + 4) = o1;
  }
}

// ---------------------------------------------------------------------------
extern "C" void kernel_launch(void* const* d_in, const int* in_sizes, int n_in,
                              void* d_out, int out_size, void* d_ws, size_t ws_size,
                              hipStream_t stream)
{
  const float* E  = (const float*)d_in[0];
  const float* WQ = (const float*)d_in[1];
  const float* WK = (const float*)d_in[2];
  const float* WV = (const float*)d_in[3];
  const size_t elems = (size_t)8*2048*256;

  unsigned short* Qb = (unsigned short*)d_ws;
  unsigned short* Ka = Qb + elems;
  unsigned short* Vf = Ka + elems;
  unsigned short* Wb = Vf + elems;                       // 3*65536 ushorts
  const size_t base = 3*elems*2 + 393216;                // 25.56 MB

  const size_t PB = (size_t)8*32*64*256*2;               // 8 MB
  const size_t MLSZ = (size_t)8*32*2*64*2*4;             // 256 KB
  if (ws_size < base) return;
  const int sched = (ws_size >= base + PB + MLSZ) ? 1 : 0;
  unsigned short* Pb = (unsigned short*)((char*)d_ws + base);
  float* ML = (float*)((char*)d_ws + base + PB);

  wconv_kernel<<<dim3(3,8), 256, 0, stream>>>(WQ, WK, WV, Wb);
  qkv_proj_kernel<<<512, 256, 0, stream>>>(E, Wb, Qb, Ka, Vf);
  attn_kernel<<<sched ? 512 : 256, 256, 0, stream>>>(Qb, Ka, Vf, (float*)d_out, sched, Pb, ML);
  if (sched) combine_kernel<<<256, 256, 0, stream>>>((float*)d_out, Pb, ML);
}